// Round 10
// baseline (334.333 us; speedup 1.0000x reference)
//
#include <hip/hip_runtime.h>
#include <math.h>

// SimpleRetention bf16-MFMA pipeline, round 10.
// out = (softmax(QK^T) * gamma^|n-m|) @ V ; Q/K = xpos(X@W), V = X@Wv
// B=8 L=2048 H=Dh=1024.
//
// Round-10 change vs round-9 (one lever):
//  - gemm256 -> 8-phase-style schedule (m201 port): per K-tile 4 fine phases
//    {READS(ks) + stage one half -> s_barrier -> setprio+8 MFMA -> s_barrier},
//    counted vmcnt(2) at tile entry (never 0 mid-loop). Staging granularity =
//    operand half (128 rows x 128B) -- rows unchanged, so round-9's verified
//    conflict-free swizzle is preserved (r8's 64B-row mistake avoided).
//    Epilogues, swizzle math, and grid decodes byte-identical to round 9.
//
// ws layout (169MB; phase-aliased):
//   [0,64MB)    Wmat bf16 [8][2048][2048]   (phase2; aliases Xb+WT of phase1)
//   [0,32MB)    Xb  bf16 [16384][1024]      (phase1)
//   [32,38MB)   WT  bf16 [3][1024][1024]    (phase1, W transposed)
//   [64,96MB)   Qb  bf16 [16384][1024]
//   [96,128MB)  Kb  bf16 [16384][1024]
//   [128,160MB) Vt  bf16 [8][1024][2048]    (V transposed per batch)
//   [160,160.5) Zp  f32  [8][8][2048]       (softmax denom partials)
//   [161,165MB) CSq u32  [2048][512]        (cos*scl_q | sin*scl_q bf16 pair)
//   [165,169MB) CSk u32  [2048][512]        (K: 1/scale)

#define LDIM 2048
#define HDIM 1024
#define MTOT 16384

typedef unsigned short u16;
typedef unsigned int u32;
typedef __attribute__((ext_vector_type(16))) float f32x16;
typedef __attribute__((ext_vector_type(8))) short s16x8;

#define GLD16(gp, lp) __builtin_amdgcn_global_load_lds( \
    (const __attribute__((address_space(1))) void*)(gp), \
    (__attribute__((address_space(3))) void*)(lp), 16, 0, 0)

__device__ __forceinline__ u16 f2bf(float f) {
    unsigned u = __float_as_uint(f);
    return (u16)((u + 0x7FFFu + ((u >> 16) & 1u)) >> 16);
}

// sin/cos(ang) via f64 revolution reduction + HW v_sin/v_cos (rev input).
__device__ __forceinline__ void sincos_rev(float ang, float* sn, float* cs) {
    double dr = (double)ang * 0.15915494309189535;   // 1/(2*pi)
    dr -= __builtin_floor(dr);
    float fr = (float)dr;
    float s_, c_;
    asm("v_sin_f32 %0, %1" : "=v"(s_) : "v"(fr));
    asm("v_cos_f32 %0, %1" : "=v"(c_) : "v"(fr));
    *sn = s_; *cs = c_;
}

// C/D mapping for mfma_f32_32x32x16_bf16 (HW-verified m74/m101):
//   col = lane&31, row = (reg&3) + 8*(reg>>2) + 4*(lane>>5), reg in [0,16)
#define ROW32(reg, laneHi) (((reg) & 3) + 8 * ((reg) >> 2) + 4 * (laneHi))

// ---------------------------------------------------------------------------
// gemm256, 8-phase schedule: 256x256 tile, BK=64, 512 thr = 8 waves (2m x 4n),
// wave C = 128x64 = 4x2 frags of 32x32x16. LDS 2 dbuf x 64KB; per dbuf:
// A-half0 [0,16K), A-half1 [16K,32K), B-half0 [32K,48K), B-half1 [48K,64K);
// rows 128B, XOR-swizzle slot' = slot^(row&7) (conflict-free), inverse on
// GLD16 source. Halves of tile t+1 staged at tile-t entry + phases 0..2;
// tile-entry s_waitcnt vmcnt(2) confirms tile t resident while the newest
// half stays in flight (vmcnt(0) only on the peeled last tile).
// Per phase: {6 ds_read ; 1 half stage ; barrier ; setprio+8 MFMA ; barrier}.
// ---------------------------------------------------------------------------
__device__ __forceinline__ void gemm256(const u16* __restrict__ A,
                                        const u16* __restrict__ B,
                                        int lda, int ldb, int K, int m0, int n0,
                                        char* smem, int tid, f32x16 (*acc)[2])
{
    const int wv = tid >> 6, ln = tid & 63;
    const int wm = wv >> 2, wn = wv & 3;
    const int lane31 = ln & 31, laneHi = ln >> 5;
    const int srow = tid >> 3;                        // 0..63 staging row/round
    const int scol = ((tid & 7) ^ (srow & 7)) * 8;    // inverse-swizzled source

    // incremental per-thread global source pointers (advance 64 elems/tile)
    const u16* ap[4];
    const u16* bp[4];
#pragma unroll
    for (int r = 0; r < 4; ++r) {
        ap[r] = A + (size_t)(m0 + r * 64 + srow) * lda + scol;
        bp[r] = B + (size_t)(n0 + r * 64 + srow) * ldb + scol;
    }

    // swizzled LDS fragment base byte offsets; per-ks XOR (ks<<5)
    int abyte[4], bbyte[2];
    const int slot_r = (laneHi ^ (lane31 & 7)) << 4;
#pragma unroll
    for (int fm = 0; fm < 4; ++fm)
        abyte[fm] = (wm * 128 + fm * 32 + lane31) * 128 + slot_r;
#pragma unroll
    for (int fn = 0; fn < 2; ++fn)
        bbyte[fn] = 32768 + (wn * 64 + fn * 32 + lane31) * 128 + slot_r;

    // half-tile stages: 2 GLD16/thread each (16KB = 128 rows x 128B, linear)
#define SGA0(e_) do{ char* d_=smem+(e_)*65536+tid*16;       GLD16(ap[0],d_); GLD16(ap[1],d_+8192); ap[0]+=64; ap[1]+=64; }while(0)
#define SGA1(e_) do{ char* d_=smem+(e_)*65536+16384+tid*16; GLD16(ap[2],d_); GLD16(ap[3],d_+8192); ap[2]+=64; ap[3]+=64; }while(0)
#define SGB0(e_) do{ char* d_=smem+(e_)*65536+32768+tid*16; GLD16(bp[0],d_); GLD16(bp[1],d_+8192); bp[0]+=64; bp[1]+=64; }while(0)
#define SGB1(e_) do{ char* d_=smem+(e_)*65536+49152+tid*16; GLD16(bp[2],d_); GLD16(bp[3],d_+8192); bp[2]+=64; bp[3]+=64; }while(0)

#define READS(Bb_, ks) do {                                                   \
        _Pragma("unroll") for (int fm_ = 0; fm_ < 4; ++fm_)                   \
            af[fm_] = *(const s16x8*)((Bb_) + (abyte[fm_] ^ ((ks) << 5)));    \
        _Pragma("unroll") for (int fn_ = 0; fn_ < 2; ++fn_)                   \
            bf[fn_] = *(const s16x8*)((Bb_) + (bbyte[fn_] ^ ((ks) << 5)));    \
    } while (0)

#define MFMA8 do { __builtin_amdgcn_s_setprio(1);                             \
        _Pragma("unroll") for (int fm_ = 0; fm_ < 4; ++fm_)                   \
            _Pragma("unroll") for (int fn_ = 0; fn_ < 2; ++fn_)               \
                acc[fm_][fn_] = __builtin_amdgcn_mfma_f32_32x32x16_bf16(      \
                    af[fm_], bf[fn_], acc[fm_][fn_], 0, 0, 0);                \
        __builtin_amdgcn_s_setprio(0); } while (0)

#define BAR do { __builtin_amdgcn_s_barrier();                                \
                 __builtin_amdgcn_sched_barrier(0); } while (0)

    const int nk = K >> 6;

    // prologue: stage all 4 halves of tile 0 (8 loads/thread)
    SGA0(0); SGB0(0); SGA1(0); SGB1(0);

#pragma unroll 1
    for (int t = 0; t < nk; ++t) {
        const int d = t & 1, e = d ^ 1;
        const bool pre = (t + 1 < nk);
        const char* Bb = smem + d * 65536;
        s16x8 af[4], bf[2];

        // tile entry: issue next A-half0, then confirm tile t fully resident
        // (its 8 loads are older than the 2 just issued -> vmcnt(2)).
        if (pre) { SGA0(e); asm volatile("s_waitcnt vmcnt(2)" ::: "memory"); }
        else     {          asm volatile("s_waitcnt vmcnt(0)" ::: "memory"); }
        BAR;
        READS(Bb, 0); if (pre) SGB0(e); BAR; MFMA8; BAR;
        READS(Bb, 1); if (pre) SGA1(e); BAR; MFMA8; BAR;
        READS(Bb, 2); if (pre) SGB1(e); BAR; MFMA8; BAR;
        READS(Bb, 3);                   BAR; MFMA8; BAR;
        // post-MFMA barriers guarantee every wave's ds_reads of dbuf e
        // (tile t-1) drained before the next tile's stages overwrite it.
    }
    __syncthreads();   // full drain; epilogue may reuse smem
#undef SGA0
#undef SGA1
#undef SGB0
#undef SGB1
#undef READS
#undef MFMA8
#undef BAR
}

// ---------------------------------------------------------------------------
// prep_all: one launch, three jobs by block range.
//   [0,2048)     cast_x:  X f32 -> Xb bf16 (grid-stride over 16M/4 float4s)
//   [2048,4096)  gen_tab: xpos cos/sin*scale tables (l = bid-2048)
//   [4096,4864)  transw:  W [k][n] f32 -> WT bf16 [n][k], 64x64 tiles
// ---------------------------------------------------------------------------
__global__ __launch_bounds__(256) void prep_all(
    const float* __restrict__ X,
    const float* __restrict__ Wq, const float* __restrict__ Wk,
    const float* __restrict__ Wv,
    u16* __restrict__ Xb, u16* __restrict__ WT,
    u32* __restrict__ CSq, u32* __restrict__ CSk)
{
    __shared__ float L[64][65];
    const int bid = blockIdx.x;
    if (bid < 2048) {
        const int n4 = MTOT * HDIM / 4;
        int i = bid * 256 + threadIdx.x;
        const int stride = 2048 * 256;
        for (; i < n4; i += stride) {
            float4 v = ((const float4*)X)[i];
            ushort4 o = make_ushort4(f2bf(v.x), f2bf(v.y), f2bf(v.z), f2bf(v.w));
            ((ushort4*)Xb)[i] = o;
        }
    } else if (bid < 4096) {
        const int l = bid - 2048;
        for (int ih = threadIdx.x; ih < 512; ih += 256) {
            float invf = exp2f(-13.287712379549449f * (1.f / 512.f) * (float)ih);
            float sn, cs;
            sincos_rev((float)l * invf, &sn, &cs);
            float l2sv = log2f(((float)(2 * ih) + 409.6f) * (1.f / 1433.6f));
            float e = (float)l * (1.f / 512.f) * l2sv;
            float sq = exp2f(e), sk = exp2f(-e);
            CSq[l * 512 + ih] = (u32)f2bf(cs * sq) | ((u32)f2bf(sn * sq) << 16);
            CSk[l * 512 + ih] = (u32)f2bf(cs * sk) | ((u32)f2bf(sn * sk) << 16);
        }
    } else {
        const int r = bid - 4096;            // [0,768) = 3 z x 16 y x 16 x
        const int z = r >> 8;
        const int y = (r >> 4) & 15;
        const int x = r & 15;
        const float* Wz = (z == 0) ? Wq : (z == 1) ? Wk : Wv;
        u16* Oz = WT + (size_t)z * HDIM * HDIM;
        const int k0 = y * 64, n0 = x * 64;
        const int t = threadIdx.x;
        const int r_ = t >> 4, c4 = (t & 15) * 4;
#pragma unroll
        for (int it = 0; it < 4; ++it) {
            const int row = it * 16 + r_;
            float4 v = *(const float4*)&Wz[(size_t)(k0 + row) * HDIM + n0 + c4];
            L[row][c4 + 0] = v.x; L[row][c4 + 1] = v.y;
            L[row][c4 + 2] = v.z; L[row][c4 + 3] = v.w;
        }
        __syncthreads();
#pragma unroll
        for (int it = 0; it < 4; ++it) {
            const int orow = it * 16 + r_;   // n-local
            ushort4 o = make_ushort4(f2bf(L[c4 + 0][orow]), f2bf(L[c4 + 1][orow]),
                                     f2bf(L[c4 + 2][orow]), f2bf(L[c4 + 3][orow]));
            *(ushort4*)&Oz[(size_t)(n0 + orow) * HDIM + k0 + c4] = o;
        }
    }
}

// ---------------------------------------------------------------------------
// K1: {Q,K,V} = X@W, xpos fused via tables for Q/K, V stored transposed.
// grid 768 x 512thr. decode: xcd(8) | m8(8) n(4) z(3); xcd owns batch xcd
// (2048 rows = 4MB X-chunk hot in its L2 across the n x z sweep).
// ---------------------------------------------------------------------------
__global__ __launch_bounds__(512, 2) void qkv_gemm(
    const u16* __restrict__ Xb, const u16* __restrict__ WT,
    const u32* __restrict__ CSq, const u32* __restrict__ CSk,
    u16* __restrict__ Qb, u16* __restrict__ Kb, u16* __restrict__ Vt)
{
    __shared__ __align__(16) char smem[256 * 264 * 2];   // >= 2*65536
    const int bid = blockIdx.x;
    const int xcd = bid & 7, t = bid >> 3;   // t in [0,96)
    const int m8 = t & 7;
    const int n_ = (t >> 3) & 3;
    const int z  = t >> 5;
    const int m0 = (xcd * 8 + m8) * 256;
    const int n0 = n_ * 256;
    const int tid = threadIdx.x;

    f32x16 acc[4][2] = {};

    gemm256(Xb, WT + (size_t)z * HDIM * HDIM, HDIM, HDIM, HDIM, m0, n0, smem, tid, acc);

    const int wv = tid >> 6, ln = tid & 63;
    const int wm = wv >> 2, wn = wv & 3;
    const int lane31 = ln & 31, laneHi = ln >> 5;
    const int l0 = m0 & (LDIM - 1);
    u16* T = (u16*)smem;   // [256][264]

    if (z < 2) {
        const u32* CS = (z == 0) ? CSq : CSk;
#pragma unroll
        for (int fn = 0; fn < 2; ++fn) {
            const int gc = n0 + wn * 64 + fn * 32 + lane31;
            const int ih = gc >> 1;
            const float sgn = (gc & 1) ? 1.f : -1.f;
            const u32* tb = CS + (size_t)l0 * 512 + ih;
#pragma unroll
            for (int fm = 0; fm < 4; ++fm) {
#pragma unroll
                for (int reg = 0; reg < 16; ++reg) {
                    const int rowl = wm * 128 + fm * 32 + ROW32(reg, laneHi);
                    u32 v = tb[(size_t)rowl * 512];
                    float cs = __uint_as_float(v << 16);
                    float sn = __uint_as_float(v & 0xFFFF0000u);
                    float c = acc[fm][fn][reg];
                    float p = __shfl_xor(c, 1);   // even<->odd column partner
                    T[rowl * 264 + wn * 64 + fn * 32 + lane31] =
                        f2bf(c * cs + sgn * p * sn);
                }
            }
        }
        __syncthreads();
        u16* Out = (z == 0) ? Qb : Kb;
        const int row_ = tid >> 5, slot = tid & 31;
#pragma unroll
        for (int g = 0; g < 16; ++g) {
            const int row = g * 16 + row_;
            s16x8 v = *(const s16x8*)&T[row * 264 + slot * 8];
            *(s16x8*)&Out[(size_t)(m0 + row) * HDIM + n0 + slot * 8] = v;
        }
    } else {
        // V: repack transposed  T[n_local][m_local]
#pragma unroll
        for (int fn = 0; fn < 2; ++fn)
#pragma unroll
            for (int fm = 0; fm < 4; ++fm)
#pragma unroll
                for (int reg = 0; reg < 16; ++reg)
                    T[(wn * 64 + fn * 32 + lane31) * 264 +
                      wm * 128 + fm * 32 + ROW32(reg, laneHi)] =
                        f2bf(acc[fm][fn][reg]);
        __syncthreads();
        const int b = m0 >> 11;
        const int row_ = tid >> 5, slot = tid & 31;
#pragma unroll
        for (int g = 0; g < 16; ++g) {
            const int row = g * 16 + row_;   // n-local (d index)
            s16x8 v = *(const s16x8*)&T[row * 264 + slot * 8];
            *(s16x8*)&Vt[((size_t)b * HDIM + n0 + row) * LDIM + l0 + slot * 8] = v;
        }
    }
}

// ---------------------------------------------------------------------------
// K2a: W = exp(s)*gamma^|q-k| (bf16) + Z partials (fp32, deterministic).
// grid 512 x 512thr: b = bid&7 (XCD-pinned). decode: nt(8) mt(8) --
// 4MB Q_b hot in XCD L2 across the nt sweep.
// ---------------------------------------------------------------------------
__global__ __launch_bounds__(512, 2) void qk_gemm(
    const u16* __restrict__ Q, const u16* __restrict__ Km,
    u16* __restrict__ Wm, float* __restrict__ Zp)
{
    __shared__ __align__(16) char smem[256 * 264 * 2];
    __shared__ float Zl[4][256];
    const int bid = blockIdx.x;
    const int b = bid & 7, t = bid >> 3;     // t in [0,64)
    const int mt = t & 7;
    const int nt = t >> 3;                   // [0,8)
    const int m0 = mt * 256;
    const int n0 = nt * 256;
    const int tid = threadIdx.x;

    f32x16 acc[4][2] = {};

    gemm256(Q + (size_t)b * LDIM * HDIM, Km + (size_t)b * LDIM * HDIM,
            HDIM, HDIM, HDIM, m0, n0, smem, tid, acc);

    const int wv = tid >> 6, ln = tid & 63;
    const int wm = wv >> 2, wn = wv & 3;
    const int lane31 = ln & 31, laneHi = ln >> 5;
    u16* T = (u16*)smem;   // [256][264]
    const float LOG2E = 1.4426950408889634f;
    const float LOG2G = -0.15200309344504997f;   // log2(0.9)

#pragma unroll
    for (int fm = 0; fm < 4; ++fm) {
        float ps[16];
#pragma unroll
        for (int reg = 0; reg < 16; ++reg) ps[reg] = 0.f;
#pragma unroll
        for (int fn = 0; fn < 2; ++fn) {
            const int gk = n0 + wn * 64 + fn * 32 + lane31;
#pragma unroll
            for (int reg = 0; reg < 16; ++reg) {
                const int mloc = wm * 128 + fm * 32 + ROW32(reg, laneHi);
                const int gq = m0 + mloc;
                float t1 = acc[fm][fn][reg] * LOG2E;
                float e = exp2f(t1);
                int dd = gq - gk; dd = dd < 0 ? -dd : dd;
                ps[reg] += e;
                T[mloc * 264 + wn * 64 + fn * 32 + lane31] =
                    f2bf(exp2f(t1 + (float)dd * LOG2G));
            }
        }
        // reduce e-sums across the 32 column-lanes
#pragma unroll
        for (int reg = 0; reg < 16; ++reg) {
            float s = ps[reg];
            s += __shfl_xor(s, 1); s += __shfl_xor(s, 2);
            s += __shfl_xor(s, 4); s += __shfl_xor(s, 8);
            s += __shfl_xor(s, 16);
            if (lane31 == 0)
                Zl[wn][wm * 128 + fm * 32 + ROW32(reg, laneHi)] = s;
        }
    }
    __syncthreads();

    const int row_ = tid >> 5, slot = tid & 31;
#pragma unroll
    for (int g = 0; g < 16; ++g) {
        const int row = g * 16 + row_;
        s16x8 v = *(const s16x8*)&T[row * 264 + slot * 8];
        *(s16x8*)&Wm[((size_t)b * LDIM + m0 + row) * LDIM + n0 + slot * 8] = v;
    }
    if (tid < 256)
        Zp[((size_t)b * 8 + nt) * LDIM + m0 + tid] =
            Zl[0][tid] + Zl[1][tid] + Zl[2][tid] + Zl[3][tid];
}

// ---------------------------------------------------------------------------
// K2b: O = (W @ V) / Z  (fp32 out).  grid 256 x 512thr: b=bid&7.
// decode: mtH(2) nt(4) mt4(4) -- 4MB W-chunk hot across the nt sweep.
// ---------------------------------------------------------------------------
__global__ __launch_bounds__(512, 2) void pv_gemm(
    const u16* __restrict__ Wm, const u16* __restrict__ Vt,
    const float* __restrict__ Zp, float* __restrict__ Out)
{
    __shared__ __align__(16) char smem[2 * 65536];
    __shared__ float Zinv[256];
    const int bid = blockIdx.x;
    const int b = bid & 7, t = bid >> 3;     // t in [0,32)
    const int mt4 = t & 3;
    const int nt = (t >> 2) & 3;
    const int mtH = t >> 4;                  // {0,1}
    const int m0 = (mtH * 4 + mt4) * 256;
    const int n0 = nt * 256;
    const int tid = threadIdx.x;

    if (tid < 256) {
        float zz = 0.f;
#pragma unroll
        for (int nb = 0; nb < 8; ++nb)
            zz += Zp[((size_t)b * 8 + nb) * LDIM + m0 + tid];
        Zinv[tid] = 1.0f / zz;
    }
    __syncthreads();   // drains Zp loads: core's counted vmcnt starts clean

    f32x16 acc[4][2] = {};

    gemm256(Wm + (size_t)b * LDIM * LDIM, Vt + (size_t)b * HDIM * LDIM,
            LDIM, LDIM, LDIM, m0, n0, smem, tid, acc);

    const int wv = tid >> 6, ln = tid & 63;
    const int wm = wv >> 2, wn = wv & 3;
    const int lane31 = ln & 31, laneHi = ln >> 5;
    float* Ob = Out + (size_t)b * LDIM * HDIM;
#pragma unroll
    for (int fm = 0; fm < 4; ++fm)
#pragma unroll
        for (int fn = 0; fn < 2; ++fn) {
            const int gn = n0 + wn * 64 + fn * 32 + lane31;
#pragma unroll
            for (int reg = 0; reg < 16; ++reg) {
                const int row = wm * 128 + fm * 32 + ROW32(reg, laneHi);
                Ob[(size_t)(m0 + row) * HDIM + gn] = acc[fm][fn][reg] * Zinv[row];
            }
        }
}

// ---------------------------------------------------------------------------
extern "C" void kernel_launch(void* const* d_in, const int* in_sizes, int n_in,
                              void* d_out, int out_size, void* d_ws, size_t ws_size,
                              hipStream_t stream)
{
    (void)in_sizes; (void)n_in; (void)out_size; (void)ws_size;
    const float* X  = (const float*)d_in[0];
    const float* Wq = (const float*)d_in[1];
    const float* Wk = (const float*)d_in[2];
    const float* Wv = (const float*)d_in[3];
    char* ws = (char*)d_ws;
    const size_t MB = 1024 * 1024;

    u16* Wmat = (u16*)ws;                 // phase2, aliases Xb+WT
    u16* Xb   = (u16*)ws;                 // phase1
    u16* WT   = (u16*)(ws + 32 * MB);     // phase1
    u16* Qb   = (u16*)(ws + 64 * MB);
    u16* Kb   = (u16*)(ws + 96 * MB);
    u16* Vt   = (u16*)(ws + 128 * MB);
    float* Zp = (float*)(ws + 160 * MB);
    u32* CSq  = (u32*)(ws + 161 * MB);
    u32* CSk  = (u32*)(ws + 165 * MB);

    prep_all<<<4864, 256, 0, stream>>>(X, Wq, Wk, Wv, Xb, WT, CSq, CSk);
    qkv_gemm<<<768, 512, 0, stream>>>(Xb, WT, CSq, CSk, Qb, Kb, Vt);
    qk_gemm<<<512, 512, 0, stream>>>(Qb, Kb, Wmat, Zp);
    pv_gemm<<<256, 512, 0, stream>>>(Wmat, Vt, Zp, (float*)d_out);
}

// Round 11
// 309.494 us; speedup vs baseline: 1.0803x; 1.0803x over previous
//
#include <hip/hip_runtime.h>
#include <math.h>

// SimpleRetention bf16-MFMA pipeline, round 11.
// out = (softmax(QK^T) * gamma^|n-m|) @ V ; Q/K = xpos(X@W), V = X@Wv
// B=8 L=2048 H=Dh=1024.
//
// Round-11 change vs round-9 (one lever; r10's K-slice phases reverted):
//  - gemm256 -> m201-faithful C-QUADRANT phases with register-cached operands:
//    16x16x32 MFMA, acc f32x4[8][4]; per K-tile: publish barrier w/ counted
//    vmcnt(4), then 4 phases {reads 12/4/8/0 ds_read_b128 + stage half ->
//    bar -> setprio + 16 MFMA -> bar}. A-quadrant + both B-halves cached in
//    VGPRs across phases (the read/MFMA ratio lever r10 missed).
//    Staging, swizzle algebra, decodes identical to round 9.
//
// ws layout (169MB; phase-aliased):
//   [0,64MB)    Wmat bf16 [8][2048][2048]   (phase2; aliases Xb+WT of phase1)
//   [0,32MB)    Xb  bf16 [16384][1024]      (phase1)
//   [32,38MB)   WT  bf16 [3][1024][1024]    (phase1, W transposed)
//   [64,96MB)   Qb  bf16 [16384][1024]
//   [96,128MB)  Kb  bf16 [16384][1024]
//   [128,160MB) Vt  bf16 [8][1024][2048]    (V transposed per batch)
//   [160,160.5) Zp  f32  [8][8][2048]       (softmax denom partials)
//   [161,165MB) CSq u32  [2048][512]        (cos*scl_q | sin*scl_q bf16 pair)
//   [165,169MB) CSk u32  [2048][512]        (K: 1/scale)

#define LDIM 2048
#define HDIM 1024
#define MTOT 16384

typedef unsigned short u16;
typedef unsigned int u32;
typedef __attribute__((ext_vector_type(4))) float f32x4;
typedef __attribute__((ext_vector_type(8))) short s16x8;

#define GLD16(gp, lp) __builtin_amdgcn_global_load_lds( \
    (const __attribute__((address_space(1))) void*)(gp), \
    (__attribute__((address_space(3))) void*)(lp), 16, 0, 0)

__device__ __forceinline__ u16 f2bf(float f) {
    unsigned u = __float_as_uint(f);
    return (u16)((u + 0x7FFFu + ((u >> 16) & 1u)) >> 16);
}

// sin/cos(ang) via f64 revolution reduction + HW v_sin/v_cos (rev input).
__device__ __forceinline__ void sincos_rev(float ang, float* sn, float* cs) {
    double dr = (double)ang * 0.15915494309189535;   // 1/(2*pi)
    dr -= __builtin_floor(dr);
    float fr = (float)dr;
    float s_, c_;
    asm("v_sin_f32 %0, %1" : "=v"(s_) : "v"(fr));
    asm("v_cos_f32 %0, %1" : "=v"(c_) : "v"(fr));
    *sn = s_; *cs = c_;
}

// ---------------------------------------------------------------------------
// gemm256q: 256x256 tile, BK=64, 512 thr = 8 waves (2m x 4n), wave C = 128x64
// as 8x4 frags of 16x16x32 (C/D: col=lane&15, row=(lane>>4)*4+reg -- verified
// here in rounds 2-3). LDS dbuf 2x64KB, 128B rows, XOR swizzle
// slot = ((kk*4+lg) ^ (lr&7)) (8 lanes/slot = conflict-free min), inverse on
// GLD16 source. Per K-tile: {stage A0,B0(t+1); vmcnt(4); BAR} then 4
// C-quadrant phases (mh,nh) = (0,0),(0,1),(1,1),(1,0):
//   {reads: A-quad 8 / B-half 4 / both / none; stage A1|B1(t+1);
//    BAR; setprio(1); 16 MFMA; setprio(0); BAR}
// A-quad + both B-halves register-cached across phases. vmcnt(0) only at the
// last tile. C = A x B^T (both row-major).
// ---------------------------------------------------------------------------
__device__ __forceinline__ void gemm256q(const u16* __restrict__ A,
                                         const u16* __restrict__ B,
                                         int lda, int ldb, int K, int m0, int n0,
                                         char* smem, int tid, f32x4 (*acc)[4])
{
    const int wv = tid >> 6, ln = tid & 63;
    const int wm = wv >> 2, wn = wv & 3;
    const int lr = ln & 15, lg = ln >> 4;
    const int srow = tid >> 3;                        // 0..63 staging row/round
    const int scol = ((tid & 7) ^ (srow & 7)) * 8;    // inverse-swizzled source

    // incremental per-thread global source pointers (advance 64 elems/tile)
    const u16* ap[4];
    const u16* bp[4];
#pragma unroll
    for (int r = 0; r < 4; ++r) {
        ap[r] = A + (size_t)(m0 + r * 64 + srow) * lda + scol;
        bp[r] = B + (size_t)(n0 + r * 64 + srow) * ldb + scol;
    }

    // fragment read bases (byte): row = (wm*128 + fm*16 + lr); B at +32KB.
    int arow[8], brow[4];
#pragma unroll
    for (int fm = 0; fm < 8; ++fm) arow[fm] = (wm * 128 + fm * 16 + lr) * 128;
#pragma unroll
    for (int fn = 0; fn < 4; ++fn) brow[fn] = 32768 + (wn * 64 + fn * 16 + lr) * 128;
    int slotb[2];   // swizzled 16B-slot byte offset per kk (row&7 == lr&7)
#pragma unroll
    for (int kk = 0; kk < 2; ++kk) slotb[kk] = (((kk << 2) | lg) ^ (lr & 7)) << 4;

#define SGA0(e_) do{ char* d_=smem+(e_)*65536+tid*16;       GLD16(ap[0],d_); GLD16(ap[1],d_+8192); ap[0]+=64; ap[1]+=64; }while(0)
#define SGA1(e_) do{ char* d_=smem+(e_)*65536+16384+tid*16; GLD16(ap[2],d_); GLD16(ap[3],d_+8192); ap[2]+=64; ap[3]+=64; }while(0)
#define SGB0(e_) do{ char* d_=smem+(e_)*65536+32768+tid*16; GLD16(bp[0],d_); GLD16(bp[1],d_+8192); bp[0]+=64; bp[1]+=64; }while(0)
#define SGB1(e_) do{ char* d_=smem+(e_)*65536+49152+tid*16; GLD16(bp[2],d_); GLD16(bp[3],d_+8192); bp[2]+=64; bp[3]+=64; }while(0)

#define RD_A(Bb_, mh) do {                                                    \
        _Pragma("unroll") for (int fm_ = 0; fm_ < 4; ++fm_)                   \
            _Pragma("unroll") for (int kk_ = 0; kk_ < 2; ++kk_)               \
                aq[fm_ * 2 + kk_] = *(const s16x8*)((Bb_) +                   \
                    arow[(mh) * 4 + fm_] + slotb[kk_]);                       \
    } while (0)
#define RD_B(Bb_, nh, dst) do {                                               \
        _Pragma("unroll") for (int fn_ = 0; fn_ < 2; ++fn_)                   \
            _Pragma("unroll") for (int kk_ = 0; kk_ < 2; ++kk_)               \
                dst[fn_ * 2 + kk_] = *(const s16x8*)((Bb_) +                  \
                    brow[(nh) * 2 + fn_] + slotb[kk_]);                       \
    } while (0)

#define MFMA16(mh, nh, bq_) do { __builtin_amdgcn_s_setprio(1);               \
        _Pragma("unroll") for (int fm_ = 0; fm_ < 4; ++fm_)                   \
            _Pragma("unroll") for (int fn_ = 0; fn_ < 2; ++fn_)               \
                _Pragma("unroll") for (int kk_ = 0; kk_ < 2; ++kk_)           \
                    acc[(mh) * 4 + fm_][(nh) * 2 + fn_] =                     \
                        __builtin_amdgcn_mfma_f32_16x16x32_bf16(              \
                            aq[fm_ * 2 + kk_], bq_[fn_ * 2 + kk_],            \
                            acc[(mh) * 4 + fm_][(nh) * 2 + fn_], 0, 0, 0);    \
        __builtin_amdgcn_s_setprio(0); } while (0)

#define BAR do { __builtin_amdgcn_sched_barrier(0);                           \
                 __builtin_amdgcn_s_barrier();                                \
                 __builtin_amdgcn_sched_barrier(0); } while (0)

    const int nk = K >> 6;

    // prologue: stage all of tile 0
    SGA0(0); SGB0(0); SGA1(0); SGB1(0);

    s16x8 aq[8], b0[4], b1[4];

#pragma unroll 1
    for (int t = 0; t < nk; ++t) {
        const int d = t & 1, e = d ^ 1;
        const bool pre = (t + 1 < nk);
        const char* Bb = smem + d * 65536;

        // tile entry: issue t+1's A0,B0; counted wait publishes tile t.
        if (pre) { SGA0(e); SGB0(e);
                   asm volatile("s_waitcnt vmcnt(4)" ::: "memory"); }
        else     { asm volatile("s_waitcnt vmcnt(0)" ::: "memory"); }
        BAR;
        // ph0: quadrant (0,0) -- reads A-quad0 (8) + B-half0 (4)
        RD_A(Bb, 0); RD_B(Bb, 0, b0); if (pre) SGA1(e);
        BAR; MFMA16(0, 0, b0); BAR;
        // ph1: quadrant (0,1) -- reads B-half1 (4); A-quad0 cached
        RD_B(Bb, 1, b1); if (pre) SGB1(e);
        BAR; MFMA16(0, 1, b1); BAR;
        // ph2: quadrant (1,1) -- reads A-quad1 (8); B-half1 cached
        RD_A(Bb, 1);
        BAR; MFMA16(1, 1, b1); BAR;
        // ph3: quadrant (1,0) -- no reads; both operands cached
        BAR; MFMA16(1, 0, b0); BAR;
    }
    __syncthreads();   // full drain; epilogue may reuse smem
#undef SGA0
#undef SGA1
#undef SGB0
#undef SGB1
#undef RD_A
#undef RD_B
#undef MFMA16
#undef BAR
}

// ---------------------------------------------------------------------------
// prep_all: one launch, three jobs by block range.
//   [0,2048)     cast_x:  X f32 -> Xb bf16 (grid-stride over 16M/4 float4s)
//   [2048,4096)  gen_tab: xpos cos/sin*scale tables (l = bid-2048)
//   [4096,4864)  transw:  W [k][n] f32 -> WT bf16 [n][k], 64x64 tiles
// ---------------------------------------------------------------------------
__global__ __launch_bounds__(256) void prep_all(
    const float* __restrict__ X,
    const float* __restrict__ Wq, const float* __restrict__ Wk,
    const float* __restrict__ Wv,
    u16* __restrict__ Xb, u16* __restrict__ WT,
    u32* __restrict__ CSq, u32* __restrict__ CSk)
{
    __shared__ float L[64][65];
    const int bid = blockIdx.x;
    if (bid < 2048) {
        const int n4 = MTOT * HDIM / 4;
        int i = bid * 256 + threadIdx.x;
        const int stride = 2048 * 256;
        for (; i < n4; i += stride) {
            float4 v = ((const float4*)X)[i];
            ushort4 o = make_ushort4(f2bf(v.x), f2bf(v.y), f2bf(v.z), f2bf(v.w));
            ((ushort4*)Xb)[i] = o;
        }
    } else if (bid < 4096) {
        const int l = bid - 2048;
        for (int ih = threadIdx.x; ih < 512; ih += 256) {
            float invf = exp2f(-13.287712379549449f * (1.f / 512.f) * (float)ih);
            float sn, cs;
            sincos_rev((float)l * invf, &sn, &cs);
            float l2sv = log2f(((float)(2 * ih) + 409.6f) * (1.f / 1433.6f));
            float e = (float)l * (1.f / 512.f) * l2sv;
            float sq = exp2f(e), sk = exp2f(-e);
            CSq[l * 512 + ih] = (u32)f2bf(cs * sq) | ((u32)f2bf(sn * sq) << 16);
            CSk[l * 512 + ih] = (u32)f2bf(cs * sk) | ((u32)f2bf(sn * sk) << 16);
        }
    } else {
        const int r = bid - 4096;            // [0,768) = 3 z x 16 y x 16 x
        const int z = r >> 8;
        const int y = (r >> 4) & 15;
        const int x = r & 15;
        const float* Wz = (z == 0) ? Wq : (z == 1) ? Wk : Wv;
        u16* Oz = WT + (size_t)z * HDIM * HDIM;
        const int k0 = y * 64, n0 = x * 64;
        const int t = threadIdx.x;
        const int r_ = t >> 4, c4 = (t & 15) * 4;
#pragma unroll
        for (int it = 0; it < 4; ++it) {
            const int row = it * 16 + r_;
            float4 v = *(const float4*)&Wz[(size_t)(k0 + row) * HDIM + n0 + c4];
            L[row][c4 + 0] = v.x; L[row][c4 + 1] = v.y;
            L[row][c4 + 2] = v.z; L[row][c4 + 3] = v.w;
        }
        __syncthreads();
#pragma unroll
        for (int it = 0; it < 4; ++it) {
            const int orow = it * 16 + r_;   // n-local
            ushort4 o = make_ushort4(f2bf(L[c4 + 0][orow]), f2bf(L[c4 + 1][orow]),
                                     f2bf(L[c4 + 2][orow]), f2bf(L[c4 + 3][orow]));
            *(ushort4*)&Oz[(size_t)(n0 + orow) * HDIM + k0 + c4] = o;
        }
    }
}

// ---------------------------------------------------------------------------
// K1: {Q,K,V} = X@W, xpos fused via tables for Q/K, V stored transposed.
// grid 768 x 512thr. decode: xcd(8) | m8(8) n(4) z(3); xcd owns batch xcd.
// ---------------------------------------------------------------------------
__global__ __launch_bounds__(512, 2) void qkv_gemm(
    const u16* __restrict__ Xb, const u16* __restrict__ WT,
    const u32* __restrict__ CSq, const u32* __restrict__ CSk,
    u16* __restrict__ Qb, u16* __restrict__ Kb, u16* __restrict__ Vt)
{
    __shared__ __align__(16) char smem[256 * 264 * 2];   // >= 2*65536
    const int bid = blockIdx.x;
    const int xcd = bid & 7, t = bid >> 3;   // t in [0,96)
    const int m8 = t & 7;
    const int n_ = (t >> 3) & 3;
    const int z  = t >> 5;
    const int m0 = (xcd * 8 + m8) * 256;
    const int n0 = n_ * 256;
    const int tid = threadIdx.x;

    f32x4 acc[8][4] = {};

    gemm256q(Xb, WT + (size_t)z * HDIM * HDIM, HDIM, HDIM, HDIM, m0, n0, smem, tid, acc);

    const int wv = tid >> 6, ln = tid & 63;
    const int wm = wv >> 2, wn = wv & 3;
    const int lr = ln & 15, lg = ln >> 4;
    const int l0 = m0 & (LDIM - 1);
    u16* T = (u16*)smem;   // [256][264]

    if (z < 2) {
        const u32* CS = (z == 0) ? CSq : CSk;
#pragma unroll
        for (int fn = 0; fn < 4; ++fn) {
            const int gc = n0 + wn * 64 + fn * 16 + lr;
            const int ih = gc >> 1;
            const float sgn = (gc & 1) ? 1.f : -1.f;
            const u32* tb = CS + (size_t)l0 * 512 + ih;
#pragma unroll
            for (int fm = 0; fm < 8; ++fm) {
#pragma unroll
                for (int reg = 0; reg < 4; ++reg) {
                    const int rowl = wm * 128 + fm * 16 + lg * 4 + reg;
                    u32 v = tb[(size_t)rowl * 512];
                    float cs = __uint_as_float(v << 16);
                    float sn = __uint_as_float(v & 0xFFFF0000u);
                    float c = acc[fm][fn][reg];
                    float p = __shfl_xor(c, 1);   // even<->odd column partner
                    T[rowl * 264 + wn * 64 + fn * 16 + lr] =
                        f2bf(c * cs + sgn * p * sn);
                }
            }
        }
        __syncthreads();
        u16* Out = (z == 0) ? Qb : Kb;
        const int row_ = tid >> 5, slot = tid & 31;
#pragma unroll
        for (int g = 0; g < 16; ++g) {
            const int row = g * 16 + row_;
            s16x8 v = *(const s16x8*)&T[row * 264 + slot * 8];
            *(s16x8*)&Out[(size_t)(m0 + row) * HDIM + n0 + slot * 8] = v;
        }
    } else {
        // V: repack transposed  T[n_local][m_local]; reg 0..3 pack to ushort4
#pragma unroll
        for (int fn = 0; fn < 4; ++fn)
#pragma unroll
            for (int fm = 0; fm < 8; ++fm) {
                ushort4 o = make_ushort4(f2bf(acc[fm][fn][0]), f2bf(acc[fm][fn][1]),
                                         f2bf(acc[fm][fn][2]), f2bf(acc[fm][fn][3]));
                *(ushort4*)&T[(wn * 64 + fn * 16 + lr) * 264 +
                              wm * 128 + fm * 16 + lg * 4] = o;
            }
        __syncthreads();
        const int b = m0 >> 11;
        const int row_ = tid >> 5, slot = tid & 31;
#pragma unroll
        for (int g = 0; g < 16; ++g) {
            const int row = g * 16 + row_;   // n-local (d index)
            s16x8 v = *(const s16x8*)&T[row * 264 + slot * 8];
            *(s16x8*)&Vt[((size_t)b * HDIM + n0 + row) * LDIM + l0 + slot * 8] = v;
        }
    }
}

// ---------------------------------------------------------------------------
// K2a: W = exp(s)*gamma^|q-k| (bf16) + Z partials (fp32, deterministic).
// grid 512 x 512thr: b = bid&7 (XCD-pinned). decode: nt(8) mt(8).
// ---------------------------------------------------------------------------
__global__ __launch_bounds__(512, 2) void qk_gemm(
    const u16* __restrict__ Q, const u16* __restrict__ Km,
    u16* __restrict__ Wm, float* __restrict__ Zp)
{
    __shared__ __align__(16) char smem[256 * 264 * 2];
    __shared__ float Zl[4][256];
    const int bid = blockIdx.x;
    const int b = bid & 7, t = bid >> 3;     // t in [0,64)
    const int mt = t & 7;
    const int nt = t >> 3;                   // [0,8)
    const int m0 = mt * 256;
    const int n0 = nt * 256;
    const int tid = threadIdx.x;

    f32x4 acc[8][4] = {};

    gemm256q(Q + (size_t)b * LDIM * HDIM, Km + (size_t)b * LDIM * HDIM,
             HDIM, HDIM, HDIM, m0, n0, smem, tid, acc);

    const int wv = tid >> 6, ln = tid & 63;
    const int wm = wv >> 2, wn = wv & 3;
    const int lr = ln & 15, lg = ln >> 4;
    u16* T = (u16*)smem;   // [256][264]
    const float LOG2E = 1.4426950408889634f;
    const float LOG2G = -0.15200309344504997f;   // log2(0.9)

#pragma unroll
    for (int fm = 0; fm < 8; ++fm) {
        float ps[4] = {0.f, 0.f, 0.f, 0.f};
#pragma unroll
        for (int fn = 0; fn < 4; ++fn) {
            const int gk = n0 + wn * 64 + fn * 16 + lr;
#pragma unroll
            for (int reg = 0; reg < 4; ++reg) {
                const int mloc = wm * 128 + fm * 16 + lg * 4 + reg;
                const int gq = m0 + mloc;
                float t1 = acc[fm][fn][reg] * LOG2E;
                float e = exp2f(t1);
                int dd = gq - gk; dd = dd < 0 ? -dd : dd;
                ps[reg] += e;
                T[mloc * 264 + wn * 64 + fn * 16 + lr] =
                    f2bf(exp2f(t1 + (float)dd * LOG2G));
            }
        }
        // reduce e-sums across the 16 col-lanes of this lg-group
#pragma unroll
        for (int reg = 0; reg < 4; ++reg) {
            float s = ps[reg];
            s += __shfl_xor(s, 1); s += __shfl_xor(s, 2);
            s += __shfl_xor(s, 4); s += __shfl_xor(s, 8);
            if (lr == 0)
                Zl[wn][wm * 128 + fm * 16 + lg * 4 + reg] = s;
        }
    }
    __syncthreads();

    const int row_ = tid >> 5, slot = tid & 31;
#pragma unroll
    for (int g = 0; g < 16; ++g) {
        const int row = g * 16 + row_;
        s16x8 v = *(const s16x8*)&T[row * 264 + slot * 8];
        *(s16x8*)&Wm[((size_t)b * LDIM + m0 + row) * LDIM + n0 + slot * 8] = v;
    }
    if (tid < 256)
        Zp[((size_t)b * 8 + nt) * LDIM + m0 + tid] =
            Zl[0][tid] + Zl[1][tid] + Zl[2][tid] + Zl[3][tid];
}

// ---------------------------------------------------------------------------
// K2b: O = (W @ V) / Z  (fp32 out).  grid 256 x 512thr: b=bid&7.
// decode: mtH(2) nt(4) mt4(4).
// ---------------------------------------------------------------------------
__global__ __launch_bounds__(512, 2) void pv_gemm(
    const u16* __restrict__ Wm, const u16* __restrict__ Vt,
    const float* __restrict__ Zp, float* __restrict__ Out)
{
    __shared__ __align__(16) char smem[2 * 65536];
    __shared__ float Zinv[256];
    const int bid = blockIdx.x;
    const int b = bid & 7, t = bid >> 3;     // t in [0,32)
    const int mt4 = t & 3;
    const int nt = (t >> 2) & 3;
    const int mtH = t >> 4;                  // {0,1}
    const int m0 = (mtH * 4 + mt4) * 256;
    const int n0 = nt * 256;
    const int tid = threadIdx.x;

    if (tid < 256) {
        float zz = 0.f;
#pragma unroll
        for (int nb = 0; nb < 8; ++nb)
            zz += Zp[((size_t)b * 8 + nb) * LDIM + m0 + tid];
        Zinv[tid] = 1.0f / zz;
    }
    __syncthreads();   // drains Zp loads: core's counted vmcnt starts clean

    f32x4 acc[8][4] = {};

    gemm256q(Wm + (size_t)b * LDIM * LDIM, Vt + (size_t)b * HDIM * LDIM,
             LDIM, LDIM, LDIM, m0, n0, smem, tid, acc);

    const int wv = tid >> 6, ln = tid & 63;
    const int wm = wv >> 2, wn = wv & 3;
    const int lr = ln & 15, lg = ln >> 4;
    float* Ob = Out + (size_t)b * LDIM * HDIM;
#pragma unroll
    for (int fm = 0; fm < 8; ++fm)
#pragma unroll
        for (int fn = 0; fn < 4; ++fn) {
            const int gn = n0 + wn * 64 + fn * 16 + lr;
#pragma unroll
            for (int reg = 0; reg < 4; ++reg) {
                const int row = wm * 128 + fm * 16 + lg * 4 + reg;
                Ob[(size_t)(m0 + row) * HDIM + gn] = acc[fm][fn][reg] * Zinv[row];
            }
        }
}

// ---------------------------------------------------------------------------
extern "C" void kernel_launch(void* const* d_in, const int* in_sizes, int n_in,
                              void* d_out, int out_size, void* d_ws, size_t ws_size,
                              hipStream_t stream)
{
    (void)in_sizes; (void)n_in; (void)out_size; (void)ws_size;
    const float* X  = (const float*)d_in[0];
    const float* Wq = (const float*)d_in[1];
    const float* Wk = (const float*)d_in[2];
    const float* Wv = (const float*)d_in[3];
    char* ws = (char*)d_ws;
    const size_t MB = 1024 * 1024;

    u16* Wmat = (u16*)ws;                 // phase2, aliases Xb+WT
    u16* Xb   = (u16*)ws;                 // phase1
    u16* WT   = (u16*)(ws + 32 * MB);     // phase1
    u16* Qb   = (u16*)(ws + 64 * MB);
    u16* Kb   = (u16*)(ws + 96 * MB);
    u16* Vt   = (u16*)(ws + 128 * MB);
    float* Zp = (float*)(ws + 160 * MB);
    u32* CSq  = (u32*)(ws + 161 * MB);
    u32* CSk  = (u32*)(ws + 165 * MB);

    prep_all<<<4864, 256, 0, stream>>>(X, Wq, Wk, Wv, Xb, WT, CSq, CSk);
    qkv_gemm<<<768, 512, 0, stream>>>(Xb, WT, CSq, CSk, Qb, Kb, Vt);
    qk_gemm<<<512, 512, 0, stream>>>(Qb, Kb, Wmat, Zp);
    pv_gemm<<<256, 512, 0, stream>>>(Wmat, Vt, Zp, (float*)d_out);
}

// Round 12
// 288.832 us; speedup vs baseline: 1.1575x; 1.0715x over previous
//
#include <hip/hip_runtime.h>
#include <math.h>

// SimpleRetention bf16-MFMA pipeline, round 12.
// out = (softmax(QK^T) * gamma^|n-m|) @ V ; Q/K = xpos(X@W), V = X@Wv
// B=8 L=2048 H=Dh=1024.
//
// Round-12 change vs round-11 (one lever):
//  - HYBRID core: r7/r9's simple 2-barrier early-stage loop (measured best,
//    119-120us qkv) + r11's conflict-free 16x16 quadrant reads with
//    register-cached operands (conflicts 9.7e6 -> 2.6e5). Drops r11's
//    per-phase barriers (7 extra barriers/tile ~= the 6us qkv regression)
//    and setprio (hurts lockstep loops, m190). Everything else identical
//    to round 11.
//
// ws layout (169MB; phase-aliased):
//   [0,64MB)    Wmat bf16 [8][2048][2048]   (phase2; aliases Xb+WT of phase1)
//   [0,32MB)    Xb  bf16 [16384][1024]      (phase1)
//   [32,38MB)   WT  bf16 [3][1024][1024]    (phase1, W transposed)
//   [64,96MB)   Qb  bf16 [16384][1024]
//   [96,128MB)  Kb  bf16 [16384][1024]
//   [128,160MB) Vt  bf16 [8][1024][2048]    (V transposed per batch)
//   [160,160.5) Zp  f32  [8][8][2048]       (softmax denom partials)
//   [161,165MB) CSq u32  [2048][512]        (cos*scl_q | sin*scl_q bf16 pair)
//   [165,169MB) CSk u32  [2048][512]        (K: 1/scale)

#define LDIM 2048
#define HDIM 1024
#define MTOT 16384

typedef unsigned short u16;
typedef unsigned int u32;
typedef __attribute__((ext_vector_type(4))) float f32x4;
typedef __attribute__((ext_vector_type(8))) short s16x8;

#define GLD16(gp, lp) __builtin_amdgcn_global_load_lds( \
    (const __attribute__((address_space(1))) void*)(gp), \
    (__attribute__((address_space(3))) void*)(lp), 16, 0, 0)

__device__ __forceinline__ u16 f2bf(float f) {
    unsigned u = __float_as_uint(f);
    return (u16)((u + 0x7FFFu + ((u >> 16) & 1u)) >> 16);
}

// sin/cos(ang) via f64 revolution reduction + HW v_sin/v_cos (rev input).
__device__ __forceinline__ void sincos_rev(float ang, float* sn, float* cs) {
    double dr = (double)ang * 0.15915494309189535;   // 1/(2*pi)
    dr -= __builtin_floor(dr);
    float fr = (float)dr;
    float s_, c_;
    asm("v_sin_f32 %0, %1" : "=v"(s_) : "v"(fr));
    asm("v_cos_f32 %0, %1" : "=v"(c_) : "v"(fr));
    *sn = s_; *cs = c_;
}

// ---------------------------------------------------------------------------
// gemm256h: 256x256 tile, BK=64, 512 thr = 8 waves (2m x 4n), wave C = 128x64
// as 8x4 frags of 16x16x32 (C/D: col=lane&15, row=(lane>>4)*4+reg -- verified
// in rounds 2-3/11). LDS dbuf 2x64KB, 128B rows, XOR swizzle
// slot = ((kk*4+lg) ^ (lr&7)) (8 lanes/slot = conflict-free, r11-verified),
// inverse on GLD16 source. Loop = r7's 2-barrier shape: stage tile t+1 early
// (full tile of compute slack), one __syncthreads per tile; quadrant compute
// order (0,0),(0,1),(1,1),(1,0) with A-quad + both B-halves register-cached
// (24 ds_read_b128 per tile per wave). No intra-tile barriers, no setprio.
// C = A x B^T (both row-major).
// ---------------------------------------------------------------------------
__device__ __forceinline__ void gemm256h(const u16* __restrict__ A,
                                         const u16* __restrict__ B,
                                         int lda, int ldb, int K, int m0, int n0,
                                         char* smem, int tid, f32x4 (*acc)[4])
{
    const int wv = tid >> 6, ln = tid & 63;
    const int wm = wv >> 2, wn = wv & 3;
    const int lr = ln & 15, lg = ln >> 4;
    const int srow = tid >> 3;                        // 0..63 staging row/round
    const int scol = ((tid & 7) ^ (srow & 7)) * 8;    // inverse-swizzled source

    // incremental per-thread global source pointers (advance 64 elems/tile)
    const u16* ap[4];
    const u16* bp[4];
#pragma unroll
    for (int r = 0; r < 4; ++r) {
        ap[r] = A + (size_t)(m0 + r * 64 + srow) * lda + scol;
        bp[r] = B + (size_t)(n0 + r * 64 + srow) * ldb + scol;
    }

    // fragment read bases (byte): row = (wm*128 + fm*16 + lr); B at +32KB.
    int arow[8], brow[4];
#pragma unroll
    for (int fm = 0; fm < 8; ++fm) arow[fm] = (wm * 128 + fm * 16 + lr) * 128;
#pragma unroll
    for (int fn = 0; fn < 4; ++fn) brow[fn] = 32768 + (wn * 64 + fn * 16 + lr) * 128;
    int slotb[2];   // swizzled 16B-slot byte offset per kk (row&7 == lr&7)
#pragma unroll
    for (int kk = 0; kk < 2; ++kk) slotb[kk] = (((kk << 2) | lg) ^ (lr & 7)) << 4;

#define STAGEALL(e_) do { char* d_ = smem + (e_) * 65536 + tid * 16;          \
        _Pragma("unroll") for (int r_ = 0; r_ < 4; ++r_) {                    \
            GLD16(ap[r_], d_ + r_ * 8192);          ap[r_] += 64; }           \
        _Pragma("unroll") for (int r_ = 0; r_ < 4; ++r_) {                    \
            GLD16(bp[r_], d_ + 32768 + r_ * 8192);  bp[r_] += 64; }           \
    } while (0)

#define RD_A(Bb_, mh) do {                                                    \
        _Pragma("unroll") for (int fm_ = 0; fm_ < 4; ++fm_)                   \
            _Pragma("unroll") for (int kk_ = 0; kk_ < 2; ++kk_)               \
                aq[fm_ * 2 + kk_] = *(const s16x8*)((Bb_) +                   \
                    arow[(mh) * 4 + fm_] + slotb[kk_]);                       \
    } while (0)
#define RD_B(Bb_, nh, dst) do {                                               \
        _Pragma("unroll") for (int fn_ = 0; fn_ < 2; ++fn_)                   \
            _Pragma("unroll") for (int kk_ = 0; kk_ < 2; ++kk_)               \
                dst[fn_ * 2 + kk_] = *(const s16x8*)((Bb_) +                  \
                    brow[(nh) * 2 + fn_] + slotb[kk_]);                       \
    } while (0)

#define MFMA16(mh, nh, bq_) do {                                              \
        _Pragma("unroll") for (int fm_ = 0; fm_ < 4; ++fm_)                   \
            _Pragma("unroll") for (int fn_ = 0; fn_ < 2; ++fn_)               \
                _Pragma("unroll") for (int kk_ = 0; kk_ < 2; ++kk_)           \
                    acc[(mh) * 4 + fm_][(nh) * 2 + fn_] =                     \
                        __builtin_amdgcn_mfma_f32_16x16x32_bf16(              \
                            aq[fm_ * 2 + kk_], bq_[fn_ * 2 + kk_],            \
                            acc[(mh) * 4 + fm_][(nh) * 2 + fn_], 0, 0, 0);    \
    } while (0)

    const int nk = K >> 6;

    STAGEALL(0);
    __syncthreads();                    // drains vmcnt(0): tile 0 resident

    s16x8 aq[8], b0[4], b1[4];

#pragma unroll 1
    for (int t = 0; t < nk; ++t) {
        const int d = t & 1, e = d ^ 1;
        if (t + 1 < nk) STAGEALL(e);    // early: full tile of compute slack
        const char* Bb = smem + d * 65536;
        // quadrant order with register-cached operands (24 reads/tile)
        RD_A(Bb, 0); RD_B(Bb, 0, b0);
        MFMA16(0, 0, b0);
        RD_B(Bb, 1, b1);
        MFMA16(0, 1, b1);
        RD_A(Bb, 1);
        MFMA16(1, 1, b1);
        MFMA16(1, 0, b0);
        __syncthreads();   // drains vmcnt (t+1 resident) + orders buf reuse
    }
    __syncthreads();   // epilogue may reuse smem
#undef STAGEALL
#undef RD_A
#undef RD_B
#undef MFMA16
}

// ---------------------------------------------------------------------------
// prep_all: one launch, three jobs by block range.
//   [0,2048)     cast_x:  X f32 -> Xb bf16 (grid-stride over 16M/4 float4s)
//   [2048,4096)  gen_tab: xpos cos/sin*scale tables (l = bid-2048)
//   [4096,4864)  transw:  W [k][n] f32 -> WT bf16 [n][k], 64x64 tiles
// ---------------------------------------------------------------------------
__global__ __launch_bounds__(256) void prep_all(
    const float* __restrict__ X,
    const float* __restrict__ Wq, const float* __restrict__ Wk,
    const float* __restrict__ Wv,
    u16* __restrict__ Xb, u16* __restrict__ WT,
    u32* __restrict__ CSq, u32* __restrict__ CSk)
{
    __shared__ float L[64][65];
    const int bid = blockIdx.x;
    if (bid < 2048) {
        const int n4 = MTOT * HDIM / 4;
        int i = bid * 256 + threadIdx.x;
        const int stride = 2048 * 256;
        for (; i < n4; i += stride) {
            float4 v = ((const float4*)X)[i];
            ushort4 o = make_ushort4(f2bf(v.x), f2bf(v.y), f2bf(v.z), f2bf(v.w));
            ((ushort4*)Xb)[i] = o;
        }
    } else if (bid < 4096) {
        const int l = bid - 2048;
        for (int ih = threadIdx.x; ih < 512; ih += 256) {
            float invf = exp2f(-13.287712379549449f * (1.f / 512.f) * (float)ih);
            float sn, cs;
            sincos_rev((float)l * invf, &sn, &cs);
            float l2sv = log2f(((float)(2 * ih) + 409.6f) * (1.f / 1433.6f));
            float e = (float)l * (1.f / 512.f) * l2sv;
            float sq = exp2f(e), sk = exp2f(-e);
            CSq[l * 512 + ih] = (u32)f2bf(cs * sq) | ((u32)f2bf(sn * sq) << 16);
            CSk[l * 512 + ih] = (u32)f2bf(cs * sk) | ((u32)f2bf(sn * sk) << 16);
        }
    } else {
        const int r = bid - 4096;            // [0,768) = 3 z x 16 y x 16 x
        const int z = r >> 8;
        const int y = (r >> 4) & 15;
        const int x = r & 15;
        const float* Wz = (z == 0) ? Wq : (z == 1) ? Wk : Wv;
        u16* Oz = WT + (size_t)z * HDIM * HDIM;
        const int k0 = y * 64, n0 = x * 64;
        const int t = threadIdx.x;
        const int r_ = t >> 4, c4 = (t & 15) * 4;
#pragma unroll
        for (int it = 0; it < 4; ++it) {
            const int row = it * 16 + r_;
            float4 v = *(const float4*)&Wz[(size_t)(k0 + row) * HDIM + n0 + c4];
            L[row][c4 + 0] = v.x; L[row][c4 + 1] = v.y;
            L[row][c4 + 2] = v.z; L[row][c4 + 3] = v.w;
        }
        __syncthreads();
#pragma unroll
        for (int it = 0; it < 4; ++it) {
            const int orow = it * 16 + r_;   // n-local
            ushort4 o = make_ushort4(f2bf(L[c4 + 0][orow]), f2bf(L[c4 + 1][orow]),
                                     f2bf(L[c4 + 2][orow]), f2bf(L[c4 + 3][orow]));
            *(ushort4*)&Oz[(size_t)(n0 + orow) * HDIM + k0 + c4] = o;
        }
    }
}

// ---------------------------------------------------------------------------
// K1: {Q,K,V} = X@W, xpos fused via tables for Q/K, V stored transposed.
// grid 768 x 512thr. decode: xcd(8) | m8(8) n(4) z(3); xcd owns batch xcd.
// ---------------------------------------------------------------------------
__global__ __launch_bounds__(512, 2) void qkv_gemm(
    const u16* __restrict__ Xb, const u16* __restrict__ WT,
    const u32* __restrict__ CSq, const u32* __restrict__ CSk,
    u16* __restrict__ Qb, u16* __restrict__ Kb, u16* __restrict__ Vt)
{
    __shared__ __align__(16) char smem[256 * 264 * 2];   // >= 2*65536
    const int bid = blockIdx.x;
    const int xcd = bid & 7, t = bid >> 3;   // t in [0,96)
    const int m8 = t & 7;
    const int n_ = (t >> 3) & 3;
    const int z  = t >> 5;
    const int m0 = (xcd * 8 + m8) * 256;
    const int n0 = n_ * 256;
    const int tid = threadIdx.x;

    f32x4 acc[8][4] = {};

    gemm256h(Xb, WT + (size_t)z * HDIM * HDIM, HDIM, HDIM, HDIM, m0, n0, smem, tid, acc);

    const int wv = tid >> 6, ln = tid & 63;
    const int wm = wv >> 2, wn = wv & 3;
    const int lr = ln & 15, lg = ln >> 4;
    const int l0 = m0 & (LDIM - 1);
    u16* T = (u16*)smem;   // [256][264]

    if (z < 2) {
        const u32* CS = (z == 0) ? CSq : CSk;
#pragma unroll
        for (int fn = 0; fn < 4; ++fn) {
            const int gc = n0 + wn * 64 + fn * 16 + lr;
            const int ih = gc >> 1;
            const float sgn = (gc & 1) ? 1.f : -1.f;
            const u32* tb = CS + (size_t)l0 * 512 + ih;
#pragma unroll
            for (int fm = 0; fm < 8; ++fm) {
#pragma unroll
                for (int reg = 0; reg < 4; ++reg) {
                    const int rowl = wm * 128 + fm * 16 + lg * 4 + reg;
                    u32 v = tb[(size_t)rowl * 512];
                    float cs = __uint_as_float(v << 16);
                    float sn = __uint_as_float(v & 0xFFFF0000u);
                    float c = acc[fm][fn][reg];
                    float p = __shfl_xor(c, 1);   // even<->odd column partner
                    T[rowl * 264 + wn * 64 + fn * 16 + lr] =
                        f2bf(c * cs + sgn * p * sn);
                }
            }
        }
        __syncthreads();
        u16* Out = (z == 0) ? Qb : Kb;
        const int row_ = tid >> 5, slot = tid & 31;
#pragma unroll
        for (int g = 0; g < 16; ++g) {
            const int row = g * 16 + row_;
            s16x8 v = *(const s16x8*)&T[row * 264 + slot * 8];
            *(s16x8*)&Out[(size_t)(m0 + row) * HDIM + n0 + slot * 8] = v;
        }
    } else {
        // V: repack transposed  T[n_local][m_local]; reg 0..3 pack to ushort4
#pragma unroll
        for (int fn = 0; fn < 4; ++fn)
#pragma unroll
            for (int fm = 0; fm < 8; ++fm) {
                ushort4 o = make_ushort4(f2bf(acc[fm][fn][0]), f2bf(acc[fm][fn][1]),
                                         f2bf(acc[fm][fn][2]), f2bf(acc[fm][fn][3]));
                *(ushort4*)&T[(wn * 64 + fn * 16 + lr) * 264 +
                              wm * 128 + fm * 16 + lg * 4] = o;
            }
        __syncthreads();
        const int b = m0 >> 11;
        const int row_ = tid >> 5, slot = tid & 31;
#pragma unroll
        for (int g = 0; g < 16; ++g) {
            const int row = g * 16 + row_;   // n-local (d index)
            s16x8 v = *(const s16x8*)&T[row * 264 + slot * 8];
            *(s16x8*)&Vt[((size_t)b * HDIM + n0 + row) * LDIM + l0 + slot * 8] = v;
        }
    }
}

// ---------------------------------------------------------------------------
// K2a: W = exp(s)*gamma^|q-k| (bf16) + Z partials (fp32, deterministic).
// grid 512 x 512thr: b = bid&7 (XCD-pinned). decode: nt(8) mt(8).
// ---------------------------------------------------------------------------
__global__ __launch_bounds__(512, 2) void qk_gemm(
    const u16* __restrict__ Q, const u16* __restrict__ Km,
    u16* __restrict__ Wm, float* __restrict__ Zp)
{
    __shared__ __align__(16) char smem[256 * 264 * 2];
    __shared__ float Zl[4][256];
    const int bid = blockIdx.x;
    const int b = bid & 7, t = bid >> 3;     // t in [0,64)
    const int mt = t & 7;
    const int nt = t >> 3;                   // [0,8)
    const int m0 = mt * 256;
    const int n0 = nt * 256;
    const int tid = threadIdx.x;

    f32x4 acc[8][4] = {};

    gemm256h(Q + (size_t)b * LDIM * HDIM, Km + (size_t)b * LDIM * HDIM,
             HDIM, HDIM, HDIM, m0, n0, smem, tid, acc);

    const int wv = tid >> 6, ln = tid & 63;
    const int wm = wv >> 2, wn = wv & 3;
    const int lr = ln & 15, lg = ln >> 4;
    u16* T = (u16*)smem;   // [256][264]
    const float LOG2E = 1.4426950408889634f;
    const float LOG2G = -0.15200309344504997f;   // log2(0.9)

#pragma unroll
    for (int fm = 0; fm < 8; ++fm) {
        float ps[4] = {0.f, 0.f, 0.f, 0.f};
#pragma unroll
        for (int fn = 0; fn < 4; ++fn) {
            const int gk = n0 + wn * 64 + fn * 16 + lr;
#pragma unroll
            for (int reg = 0; reg < 4; ++reg) {
                const int mloc = wm * 128 + fm * 16 + lg * 4 + reg;
                const int gq = m0 + mloc;
                float t1 = acc[fm][fn][reg] * LOG2E;
                float e = exp2f(t1);
                int dd = gq - gk; dd = dd < 0 ? -dd : dd;
                ps[reg] += e;
                T[mloc * 264 + wn * 64 + fn * 16 + lr] =
                    f2bf(exp2f(t1 + (float)dd * LOG2G));
            }
        }
        // reduce e-sums across the 16 col-lanes of this lg-group
#pragma unroll
        for (int reg = 0; reg < 4; ++reg) {
            float s = ps[reg];
            s += __shfl_xor(s, 1); s += __shfl_xor(s, 2);
            s += __shfl_xor(s, 4); s += __shfl_xor(s, 8);
            if (lr == 0)
                Zl[wn][wm * 128 + fm * 16 + lg * 4 + reg] = s;
        }
    }
    __syncthreads();

    const int row_ = tid >> 5, slot = tid & 31;
#pragma unroll
    for (int g = 0; g < 16; ++g) {
        const int row = g * 16 + row_;
        s16x8 v = *(const s16x8*)&T[row * 264 + slot * 8];
        *(s16x8*)&Wm[((size_t)b * LDIM + m0 + row) * LDIM + n0 + slot * 8] = v;
    }
    if (tid < 256)
        Zp[((size_t)b * 8 + nt) * LDIM + m0 + tid] =
            Zl[0][tid] + Zl[1][tid] + Zl[2][tid] + Zl[3][tid];
}

// ---------------------------------------------------------------------------
// K2b: O = (W @ V) / Z  (fp32 out).  grid 256 x 512thr: b=bid&7.
// decode: mtH(2) nt(4) mt4(4).
// ---------------------------------------------------------------------------
__global__ __launch_bounds__(512, 2) void pv_gemm(
    const u16* __restrict__ Wm, const u16* __restrict__ Vt,
    const float* __restrict__ Zp, float* __restrict__ Out)
{
    __shared__ __align__(16) char smem[2 * 65536];
    __shared__ float Zinv[256];
    const int bid = blockIdx.x;
    const int b = bid & 7, t = bid >> 3;     // t in [0,32)
    const int mt4 = t & 3;
    const int nt = (t >> 2) & 3;
    const int mtH = t >> 4;                  // {0,1}
    const int m0 = (mtH * 4 + mt4) * 256;
    const int n0 = nt * 256;
    const int tid = threadIdx.x;

    if (tid < 256) {
        float zz = 0.f;
#pragma unroll
        for (int nb = 0; nb < 8; ++nb)
            zz += Zp[((size_t)b * 8 + nb) * LDIM + m0 + tid];
        Zinv[tid] = 1.0f / zz;
    }
    __syncthreads();   // Zp loads drained before the core's staging begins

    f32x4 acc[8][4] = {};

    gemm256h(Wm + (size_t)b * LDIM * LDIM, Vt + (size_t)b * HDIM * LDIM,
             LDIM, LDIM, LDIM, m0, n0, smem, tid, acc);

    const int wv = tid >> 6, ln = tid & 63;
    const int wm = wv >> 2, wn = wv & 3;
    const int lr = ln & 15, lg = ln >> 4;
    float* Ob = Out + (size_t)b * LDIM * HDIM;
#pragma unroll
    for (int fm = 0; fm < 8; ++fm)
#pragma unroll
        for (int fn = 0; fn < 4; ++fn) {
            const int gn = n0 + wn * 64 + fn * 16 + lr;
#pragma unroll
            for (int reg = 0; reg < 4; ++reg) {
                const int row = wm * 128 + fm * 16 + lg * 4 + reg;
                Ob[(size_t)(m0 + row) * HDIM + gn] = acc[fm][fn][reg] * Zinv[row];
            }
        }
}

// ---------------------------------------------------------------------------
extern "C" void kernel_launch(void* const* d_in, const int* in_sizes, int n_in,
                              void* d_out, int out_size, void* d_ws, size_t ws_size,
                              hipStream_t stream)
{
    (void)in_sizes; (void)n_in; (void)out_size; (void)ws_size;
    const float* X  = (const float*)d_in[0];
    const float* Wq = (const float*)d_in[1];
    const float* Wk = (const float*)d_in[2];
    const float* Wv = (const float*)d_in[3];
    char* ws = (char*)d_ws;
    const size_t MB = 1024 * 1024;

    u16* Wmat = (u16*)ws;                 // phase2, aliases Xb+WT
    u16* Xb   = (u16*)ws;                 // phase1
    u16* WT   = (u16*)(ws + 32 * MB);     // phase1
    u16* Qb   = (u16*)(ws + 64 * MB);
    u16* Kb   = (u16*)(ws + 96 * MB);
    u16* Vt   = (u16*)(ws + 128 * MB);
    float* Zp = (float*)(ws + 160 * MB);
    u32* CSq  = (u32*)(ws + 161 * MB);
    u32* CSk  = (u32*)(ws + 165 * MB);

    prep_all<<<4864, 256, 0, stream>>>(X, Wq, Wk, Wv, Xb, WT, CSq, CSk);
    qkv_gemm<<<768, 512, 0, stream>>>(Xb, WT, CSq, CSk, Qb, Kb, Vt);
    qk_gemm<<<512, 512, 0, stream>>>(Qb, Kb, Wmat, Zp);
    pv_gemm<<<256, 512, 0, stream>>>(Wmat, Vt, Zp, (float*)d_out);
}